// Round 2
// baseline (9202.509 us; speedup 1.0000x reference)
//
#include <hip/hip_runtime.h>

#define BB 64
#define TT 256
#define DD 512
#define HH 1024
#define NG 4096   // 4*H
#define NCLS 1000

typedef _Float16 f16;
typedef _Float16 f16x4 __attribute__((ext_vector_type(4)));
typedef _Float16 f16x8 __attribute__((ext_vector_type(8)));
typedef float f32x4 __attribute__((ext_vector_type(4)));

// ---- prep: x [B][T][D] fp32 -> x16 [T][B][D] fp16 ----
__global__ __launch_bounds__(256) void prep_x_kernel(const float* __restrict__ x,
                                                     f16* __restrict__ x16) {
  int idx = blockIdx.x * 256 + threadIdx.x;  // over T*B*(D/4)
  int d4  = idx & 127;       // D/4 = 128
  int rem = idx >> 7;
  int b   = rem & 63;
  int t   = rem >> 6;
  float4 v = *(const float4*)(x + ((size_t)b * TT + t) * DD + d4 * 4);
  f16x4 o = {(f16)v.x, (f16)v.y, (f16)v.z, (f16)v.w};
  *(f16x4*)(x16 + ((size_t)t * BB + b) * DD + d4 * 4) = o;
}

// ---- prep: Wcat[j][0:din]=W_ih[j], Wcat[j][din:K]=W_hh[j], fp16 ----
__global__ __launch_bounds__(256) void prep_w_kernel(const float* __restrict__ Wih,
                                                     const float* __restrict__ Whh,
                                                     f16* __restrict__ Wcat,
                                                     int din, int K) {
  int idx = blockIdx.x * 256 + threadIdx.x;  // over NG*K/4
  int kq  = K >> 2;
  int c4  = idx % kq;
  int row = idx / kq;
  if (row >= NG) return;
  int c = c4 * 4;
  const float* src = (c < din) ? (Wih + (size_t)row * din + c)
                               : (Whh + (size_t)row * HH + (c - din));
  float4 v = *(const float4*)src;
  f16x4 o = {(f16)v.x, (f16)v.y, (f16)v.z, (f16)v.w};
  *(f16x4*)(Wcat + (size_t)row * K + c) = o;
}

__global__ __launch_bounds__(256) void prep_b_kernel(const float* __restrict__ bih,
                                                     const float* __restrict__ bhh,
                                                     float* __restrict__ bcat) {
  int idx = blockIdx.x * 256 + threadIdx.x;
  if (idx < NG) bcat[idx] = bih[idx] + bhh[idx];
}

// ---- one LSTM timestep, fused input-proj + recurrent matmul + activations ----
// gates[b][j] = sum_k A[b][k] * Wcat[j][k],  A = concat(x_t, h_{t-1})  (fp16)
// grid: (64, 2)  -> blockIdx.x = 16 h-columns (64 blocks cover H=1024),
//                   blockIdx.y = 32-batch half
// block: 256 thr = 4 waves; wave w computes gate w for its (32 b x 16 hcol) tile
template <int DIN>
__global__ __launch_bounds__(256) void lstm_step(const f16* __restrict__ Ax,
                                                 const f16* __restrict__ hin,
                                                 const f16* __restrict__ Wcat,
                                                 const float* __restrict__ bcat,
                                                 float* __restrict__ c,
                                                 f16* __restrict__ hout) {
  constexpr int K   = DIN + HH;
  constexpr int CK  = 64;
  constexpr int LDA = CK + 8;  // +8 halves: 16B-aligned rows, 2-way banks (free)
  __shared__ f16 Al[32][LDA];
  __shared__ f16 Wl[64][LDA];
  __shared__ float gl[4][32][17];

  const int tid  = threadIdx.x;
  const int wave = tid >> 6;    // gate index i,f,g,o
  const int lane = tid & 63;
  const int lrow = lane & 15;
  const int kgrp = lane >> 4;
  const int hc0  = blockIdx.x * 16;
  const int b0   = blockIdx.y * 32;

  f32x4 acc[2] = {};

  for (int k0 = 0; k0 < K; k0 += CK) {
    // stage A chunk: 32 rows x 64 k  (256 vec8 loads, 1/thread)
    {
      int row = tid >> 3;
      int kk  = (tid & 7) * 8;
      int kg  = k0 + kk;
      const f16* asrc = (kg < DIN) ? (Ax + (size_t)(b0 + row) * DIN + kg)
                                   : (hin + (size_t)(b0 + row) * HH + (kg - DIN));
      *(f16x8*)(&Al[row][kk]) = *(const f16x8*)asrc;
    }
    // stage W chunk: 64 rows (4 gates x 16 cols) x 64 k  (512 vec8, 2/thread)
    #pragma unroll
    for (int i = 0; i < 2; i++) {
      int v   = tid + i * 256;
      int row = v >> 3;
      int kk  = (v & 7) * 8;
      int kg  = k0 + kk;
      int grow = (row >> 4) * HH + hc0 + (row & 15);
      *(f16x8*)(&Wl[row][kk]) = *(const f16x8*)(Wcat + (size_t)grow * K + kg);
    }
    __syncthreads();
    #pragma unroll
    for (int ks = 0; ks < CK; ks += 32) {
      int klo = ks + kgrp * 8;
      f16x8 bfrag = *(const f16x8*)(&Wl[wave * 16 + lrow][klo]);
      #pragma unroll
      for (int mt = 0; mt < 2; mt++) {
        f16x8 afrag = *(const f16x8*)(&Al[mt * 16 + lrow][klo]);
        acc[mt] = __builtin_amdgcn_mfma_f32_16x16x32_f16(afrag, bfrag, acc[mt], 0, 0, 0);
      }
    }
    __syncthreads();
  }

  // gate staging: C/D layout col=lane&15, row=(lane>>4)*4+reg  [m89-verified]
  #pragma unroll
  for (int mt = 0; mt < 2; mt++)
    #pragma unroll
    for (int r = 0; r < 4; r++) {
      int bl = mt * 16 + kgrp * 4 + r;
      gl[wave][bl][lrow] = acc[mt][r];
    }
  __syncthreads();

  // elementwise LSTM cell update: 32 b x 16 hcol = 512 outputs, 2/thread
  for (int i = tid; i < 32 * 16; i += 256) {
    int bl   = i >> 4;
    int j    = i & 15;
    int hcol = hc0 + j;
    int b    = b0 + bl;
    float gi = gl[0][bl][j] + bcat[hcol];
    float gf = gl[1][bl][j] + bcat[HH + hcol];
    float gg = gl[2][bl][j] + bcat[2 * HH + hcol];
    float go = gl[3][bl][j] + bcat[3 * HH + hcol];
    float si = 1.f / (1.f + __expf(-gi));
    float sf = 1.f / (1.f + __expf(-gf));
    float tg = tanhf(gg);
    float so = 1.f / (1.f + __expf(-go));
    size_t off = (size_t)b * HH + hcol;
    float cc = sf * c[off] + si * tg;
    c[off]   = cc;
    hout[off] = (f16)(so * tanhf(cc));
  }
}

// ---- FC: logits[b][cls] = b_fc[cls] + sum_k concat(h0,h1)[b][k] * Wfc[cls][k]
__global__ __launch_bounds__(256) void fc_kernel(const f16* __restrict__ h0f,
                                                 const f16* __restrict__ h1f,
                                                 const float* __restrict__ Wfc,
                                                 const float* __restrict__ bfc,
                                                 float* __restrict__ out) {
  __shared__ f16 hl[64][264];
  __shared__ float Wl[4][260];
  const int tid = threadIdx.x;
  const int cl0 = blockIdx.x * 4;
  const int b   = tid >> 2;
  const int cq  = tid & 3;
  float a = 0.f;
  for (int k0 = 0; k0 < 2 * HH; k0 += 256) {
    #pragma unroll
    for (int i = 0; i < 8; i++) {
      int v   = tid + i * 256;
      int row = v >> 5;
      int kk  = (v & 31) * 8;
      int kg  = k0 + kk;
      const f16* src = (kg < HH) ? (h0f + (size_t)row * HH + kg)
                                 : (h1f + (size_t)row * HH + (kg - HH));
      *(f16x8*)(&hl[row][kk]) = *(const f16x8*)src;
    }
    {
      int row = tid >> 6;
      int kk  = (tid & 63) * 4;
      *(float4*)(&Wl[row][kk]) = *(const float4*)(Wfc + (size_t)(cl0 + row) * (2 * HH) + k0 + kk);
    }
    __syncthreads();
    #pragma unroll 8
    for (int k = 0; k < 256; k++) a += (float)hl[b][k] * Wl[cq][k];
    __syncthreads();
  }
  out[(size_t)b * NCLS + cl0 + cq] = a + bfc[cl0 + cq];
}

extern "C" void kernel_launch(void* const* d_in, const int* in_sizes, int n_in,
                              void* d_out, int out_size, void* d_ws, size_t ws_size,
                              hipStream_t stream) {
  const float* x    = (const float*)d_in[0];
  const float* Wih0 = (const float*)d_in[1];
  const float* Whh0 = (const float*)d_in[2];
  const float* bih0 = (const float*)d_in[3];
  const float* bhh0 = (const float*)d_in[4];
  const float* Wih1 = (const float*)d_in[5];
  const float* Whh1 = (const float*)d_in[6];
  const float* bih1 = (const float*)d_in[7];
  const float* bhh1 = (const float*)d_in[8];
  const float* Wfc  = (const float*)d_in[9];
  const float* bfc  = (const float*)d_in[10];
  float* out = (float*)d_out;

  char* p = (char*)d_ws;
  auto alloc = [&](size_t bytes) {
    char* r = p;
    p += (bytes + 255) & ~(size_t)255;
    return r;
  };
  f16*   x16   = (f16*)alloc((size_t)BB * TT * DD * 2);
  f16*   outs0 = (f16*)alloc((size_t)TT * BB * HH * 2);
  f16*   Wcat0 = (f16*)alloc((size_t)NG * (DD + HH) * 2);
  f16*   Wcat1 = (f16*)alloc((size_t)NG * (HH + HH) * 2);
  float* bcat0 = (float*)alloc((size_t)NG * 4);
  float* bcat1 = (float*)alloc((size_t)NG * 4);
  float* c0    = (float*)alloc((size_t)BB * HH * 4);
  float* c1    = (float*)alloc((size_t)BB * HH * 4);
  f16*   hb0   = (f16*)alloc((size_t)BB * HH * 2);
  f16*   hb1   = (f16*)alloc((size_t)BB * HH * 2);
  f16*   zeroh = (f16*)alloc((size_t)BB * HH * 2);

  if ((size_t)(p - (char*)d_ws) > ws_size) return;  // ws too small: bail cleanly

  hipMemsetAsync(zeroh, 0, (size_t)BB * HH * 2, stream);
  hipMemsetAsync(c0, 0, (size_t)BB * HH * 4, stream);
  hipMemsetAsync(c1, 0, (size_t)BB * HH * 4, stream);

  prep_x_kernel<<<dim3(TT * BB * (DD / 4) / 256), dim3(256), 0, stream>>>(x, x16);
  prep_w_kernel<<<dim3(NG * (DD + HH) / 4 / 256), dim3(256), 0, stream>>>(Wih0, Whh0, Wcat0, DD, DD + HH);
  prep_w_kernel<<<dim3(NG * (HH + HH) / 4 / 256), dim3(256), 0, stream>>>(Wih1, Whh1, Wcat1, HH, HH + HH);
  prep_b_kernel<<<dim3(16), dim3(256), 0, stream>>>(bih0, bhh0, bcat0);
  prep_b_kernel<<<dim3(16), dim3(256), 0, stream>>>(bih1, bhh1, bcat1);

  // layer 0: h trail lives in outs0 (time-major), also the layer-1 input
  for (int t = 0; t < TT; t++) {
    const f16* hin = (t == 0) ? zeroh : outs0 + (size_t)(t - 1) * BB * HH;
    lstm_step<DD><<<dim3(HH / 16, 2), dim3(256), 0, stream>>>(
        x16 + (size_t)t * BB * DD, hin, Wcat0, bcat0, c0,
        outs0 + (size_t)t * BB * HH);
  }
  // layer 1: ping-pong h buffers; only final h needed
  for (int t = 0; t < TT; t++) {
    const f16* hin = (t == 0) ? zeroh : ((t & 1) ? hb0 : hb1);
    f16* ho = (t & 1) ? hb1 : hb0;
    lstm_step<HH><<<dim3(HH / 16, 2), dim3(256), 0, stream>>>(
        outs0 + (size_t)t * BB * HH, hin, Wcat1, bcat1, c1, ho);
  }
  // h0_final = outs0[T-1], h1_final = hb1 (t=255 odd -> hb1)
  fc_kernel<<<dim3(NCLS / 4), dim3(256), 0, stream>>>(
      outs0 + (size_t)(TT - 1) * BB * HH, hb1, Wfc, bfc, out);
}

// Round 3
// 8063.811 us; speedup vs baseline: 1.1412x; 1.1412x over previous
//
#include <hip/hip_runtime.h>

#define BB 64
#define TT 256
#define DD 512
#define HH 1024
#define NG 4096   // 4*H
#define NCLS 1000

#define NB   256   // persistent blocks (== CU count; 1 block/CU via LDS)
#define L0B  128   // blocks 0..127: layer0; 128..255: layer1
#define COLS 8     // h-columns per block
#define K0   (DD + HH)   // 1536
#define K1   (HH + HH)   // 2048
#define LDW0 (K0 + 8)    // +8 halves: row stride ≡ 4 dw mod 32 → 2-way (free)
#define LDW1 (K1 + 8)
#define DYNLDS (32 * LDW1 * 2)  // 131584 B

typedef _Float16 f16;
typedef _Float16 f16x4 __attribute__((ext_vector_type(4)));
typedef _Float16 f16x8 __attribute__((ext_vector_type(8)));
typedef float f32x4 __attribute__((ext_vector_type(4)));

#define MFMA16(af, bf, acc) __builtin_amdgcn_mfma_f32_16x16x32_f16((af), (bf), (acc), 0, 0, 0)
#define FSIG(x) (1.f / (1.f + __expf(-(x))))
#define FTANH(x) (1.f - 2.f / (__expf(2.f * (x)) + 1.f))

// ---- prep: x [B][T][D] fp32 -> x16 [T][B][D] fp16 ----
__global__ __launch_bounds__(256) void prep_x_kernel(const float* __restrict__ x,
                                                     f16* __restrict__ x16) {
  int idx = blockIdx.x * 256 + threadIdx.x;  // over T*B*(D/4)
  int d4  = idx & 127;
  int rem = idx >> 7;
  int b   = rem & 63;
  int t   = rem >> 6;
  float4 v = *(const float4*)(x + ((size_t)b * TT + t) * DD + d4 * 4);
  f16x4 o = {(f16)v.x, (f16)v.y, (f16)v.z, (f16)v.w};
  *(f16x4*)(x16 + ((size_t)t * BB + b) * DD + d4 * 4) = o;
}

// ---- prep: Wcat[j][0:din]=W_ih[j], Wcat[j][din:K]=W_hh[j], fp16 ----
__global__ __launch_bounds__(256) void prep_w_kernel(const float* __restrict__ Wih,
                                                     const float* __restrict__ Whh,
                                                     f16* __restrict__ Wcat,
                                                     int din, int K) {
  int idx = blockIdx.x * 256 + threadIdx.x;
  int kq  = K >> 2;
  int c4  = idx % kq;
  int row = idx / kq;
  if (row >= NG) return;
  int c = c4 * 4;
  const float* src = (c < din) ? (Wih + (size_t)row * din + c)
                               : (Whh + (size_t)row * HH + (c - din));
  float4 v = *(const float4*)src;
  f16x4 o = {(f16)v.x, (f16)v.y, (f16)v.z, (f16)v.w};
  *(f16x4*)(Wcat + (size_t)row * K + c) = o;
}

__global__ __launch_bounds__(256) void prep_b_kernel(const float* __restrict__ bih,
                                                     const float* __restrict__ bhh,
                                                     float* __restrict__ bcat) {
  int idx = blockIdx.x * 256 + threadIdx.x;
  if (idx < NG) bcat[idx] = bih[idx] + bhh[idx];
}

// ---- device-wide barrier (all NB blocks resident: 1 block/CU by LDS) ----
__device__ __forceinline__ void gbar(int* cnt, int* gen) {
  __syncthreads();  // drains each wave's stores (vmcnt 0) before signaling
  if (threadIdx.x == 0) {
    int g = __hip_atomic_load(gen, __ATOMIC_RELAXED, __HIP_MEMORY_SCOPE_AGENT);
    __threadfence();  // agent release: L2 writeback (cross-XCD visibility)
    int a = __hip_atomic_fetch_add(cnt, 1, __ATOMIC_RELAXED, __HIP_MEMORY_SCOPE_AGENT);
    if (a == NB - 1) {
      __hip_atomic_store(cnt, 0, __ATOMIC_RELAXED, __HIP_MEMORY_SCOPE_AGENT);
      __hip_atomic_fetch_add(gen, 1, __ATOMIC_RELEASE, __HIP_MEMORY_SCOPE_AGENT);
    } else {
      while (__hip_atomic_load(gen, __ATOMIC_RELAXED, __HIP_MEMORY_SCOPE_AGENT) == g)
        __builtin_amdgcn_s_sleep(1);
    }
    __threadfence();  // agent acquire: invalidate stale L1/L2 lines
  }
  __syncthreads();
}

// ---- persistent 2-layer LSTM ----
// Block owns 8 h-cols of one layer; weights (32 rows x K) pinned in LDS.
// Super-step s: layer0 computes t=s, layer1 computes t=s-1. One gbar/step.
// c-state entirely in registers. h double-buffered in global (parity s&1).
__global__ __launch_bounds__(256) void lstm_persistent(
    const f16* __restrict__ x16,
    const f16* __restrict__ Wcat0, const f16* __restrict__ Wcat1,
    const float* __restrict__ bcat0, const float* __restrict__ bcat1,
    f16* __restrict__ h0g, f16* __restrict__ h1g, int* __restrict__ bar) {
  extern __shared__ f16 Wl[];
  const int bid  = blockIdx.x;
  const bool L1  = (bid >= L0B);
  const int j0   = (L1 ? bid - L0B : bid) * COLS;
  const int tid  = threadIdx.x;
  const int wv   = tid >> 6;
  const int lane = tid & 63;
  const int col  = lane & 15;   // C/D: n-index (weight row within tile)
  const int kgrp = lane >> 4;   // C/D: m-subgroup; A/B frag k-chunk
  const int jc   = col & 7;
  const int K    = L1 ? K1 : K0;
  const int LDW  = L1 ? LDW1 : LDW0;
  const f16* Wsrc = L1 ? Wcat1 : Wcat0;
  const float* bc = L1 ? bcat1 : bcat0;

  // prologue: weights -> LDS. row n = gate*8 + jc  (tile0: gates i,f; tile1: g,o)
  for (int n = wv; n < 32; n += 4) {
    const f16* src = Wsrc + (size_t)((n >> 3) * HH + j0 + (n & 7)) * K;
    f16* dst = Wl + (size_t)n * LDW;
    for (int kk = lane * 8; kk < K; kk += 512)
      *(f16x8*)(dst + kk) = *(const f16x8*)(src + kk);
  }
  const float bias0 = bc[((col < 8) ? 0 : 1) * HH + j0 + jc];  // b_i / b_f
  const float bias1 = bc[((col < 8) ? 2 : 3) * HH + j0 + jc];  // b_g / b_o
  __syncthreads();

  const f16* bp0 = Wl + (size_t)col * LDW + kgrp * 8;   // B-frag base, tile0
  const f16* bp1 = bp0 + (size_t)16 * LDW;              // tile1
  const int b16  = wv * 16 + col;        // A-row (batch) this lane loads
  const int bout = wv * 16 + kgrp * 4;   // C-row (batch) base for this lane
  float creg[4] = {0.f, 0.f, 0.f, 0.f};

  int* cnt = bar;
  int* gen = bar + 1;

  for (int s = 0; s <= TT; ++s) {
    const int wrp = s & 1;
    const f16* h0r = h0g + (size_t)(wrp ^ 1) * (BB * HH);
    const f16* h1r = h1g + (size_t)(wrp ^ 1) * (BB * HH);
    f16* hw = (L1 ? h1g : h0g) + (size_t)wrp * (BB * HH);
    const bool active = L1 ? (s >= 1) : (s < TT);
    const int t = L1 ? (s - 1) : s;

    f32x4 acc0 = {0.f, 0.f, 0.f, 0.f};
    f32x4 acc1 = {0.f, 0.f, 0.f, 0.f};

    // pre-barrier: layer0 x-projection part (static input, hides barrier wait)
    if (!L1 && active) {
      const f16* ax = x16 + ((size_t)t * BB + b16) * DD + kgrp * 8;
      #pragma unroll 8
      for (int kg = 0; kg < DD; kg += 32) {
        f16x8 af = *(const f16x8*)(ax + kg);
        acc0 = MFMA16(af, *(const f16x8*)(bp0 + kg), acc0);
        acc1 = MFMA16(af, *(const f16x8*)(bp1 + kg), acc1);
      }
    }

    gbar(cnt, gen);  // publishes h writes of super-step s-1

    if (active) {
      if (!L1) {
        const f16* ah = h0r + (size_t)b16 * HH + kgrp * 8;
        #pragma unroll 8
        for (int kg = 0; kg < HH; kg += 32) {
          f16x8 af = *(const f16x8*)(ah + kg);
          acc0 = MFMA16(af, *(const f16x8*)(bp0 + DD + kg), acc0);
          acc1 = MFMA16(af, *(const f16x8*)(bp1 + DD + kg), acc1);
        }
      } else {
        const f16* a0 = h0r + (size_t)b16 * HH + kgrp * 8;
        #pragma unroll 8
        for (int kg = 0; kg < HH; kg += 32) {
          f16x8 af = *(const f16x8*)(a0 + kg);
          acc0 = MFMA16(af, *(const f16x8*)(bp0 + kg), acc0);
          acc1 = MFMA16(af, *(const f16x8*)(bp1 + kg), acc1);
        }
        const f16* a1 = h1r + (size_t)b16 * HH + kgrp * 8;
        #pragma unroll 8
        for (int kg = 0; kg < HH; kg += 32) {
          f16x8 af = *(const f16x8*)(a1 + kg);
          acc0 = MFMA16(af, *(const f16x8*)(bp0 + HH + kg), acc0);
          acc1 = MFMA16(af, *(const f16x8*)(bp1 + HH + kg), acc1);
        }
      }
      // elementwise: lane(col<8) holds i (acc0), g (acc1); partner col+8 holds f,o
      #pragma unroll
      for (int r = 0; r < 4; ++r) {
        float p0 = acc0[r] + bias0;
        float p1 = acc1[r] + bias1;
        float q0 = __shfl_xor(p0, 8);
        float q1 = __shfl_xor(p1, 8);
        if (col < 8) {
          float ig = FSIG(p0);
          float gg = FTANH(p1);
          float fg = FSIG(q0);
          float og = FSIG(q1);
          float cc = fg * creg[r] + ig * gg;
          creg[r] = cc;
          hw[(size_t)(bout + r) * HH + j0 + jc] = (f16)(og * FTANH(cc));
        }
      }
    }
  }
}

// ---- FC: logits[b][cls] = b_fc[cls] + sum_k concat(h0,h1)[b][k] * Wfc[cls][k]
__global__ __launch_bounds__(256) void fc_kernel(const f16* __restrict__ h0f,
                                                 const f16* __restrict__ h1f,
                                                 const float* __restrict__ Wfc,
                                                 const float* __restrict__ bfc,
                                                 float* __restrict__ out) {
  __shared__ f16 hl[64][264];
  __shared__ float Wl[4][260];
  const int tid = threadIdx.x;
  const int cl0 = blockIdx.x * 4;
  const int b   = tid >> 2;
  const int cq  = tid & 3;
  float a = 0.f;
  for (int k0 = 0; k0 < 2 * HH; k0 += 256) {
    #pragma unroll
    for (int i = 0; i < 8; i++) {
      int v   = tid + i * 256;
      int row = v >> 5;
      int kk  = (v & 31) * 8;
      int kg  = k0 + kk;
      const f16* src = (kg < HH) ? (h0f + (size_t)row * HH + kg)
                                 : (h1f + (size_t)row * HH + (kg - HH));
      *(f16x8*)(&hl[row][kk]) = *(const f16x8*)src;
    }
    {
      int row = tid >> 6;
      int kk  = (tid & 63) * 4;
      *(float4*)(&Wl[row][kk]) = *(const float4*)(Wfc + (size_t)(cl0 + row) * (2 * HH) + k0 + kk);
    }
    __syncthreads();
    #pragma unroll 8
    for (int k = 0; k < 256; k++) a += (float)hl[b][k] * Wl[cq][k];
    __syncthreads();
  }
  out[(size_t)b * NCLS + cl0 + cq] = a + bfc[cl0 + cq];
}

extern "C" void kernel_launch(void* const* d_in, const int* in_sizes, int n_in,
                              void* d_out, int out_size, void* d_ws, size_t ws_size,
                              hipStream_t stream) {
  const float* x    = (const float*)d_in[0];
  const float* Wih0 = (const float*)d_in[1];
  const float* Whh0 = (const float*)d_in[2];
  const float* bih0 = (const float*)d_in[3];
  const float* bhh0 = (const float*)d_in[4];
  const float* Wih1 = (const float*)d_in[5];
  const float* Whh1 = (const float*)d_in[6];
  const float* bih1 = (const float*)d_in[7];
  const float* bhh1 = (const float*)d_in[8];
  const float* Wfc  = (const float*)d_in[9];
  const float* bfc  = (const float*)d_in[10];
  float* out = (float*)d_out;

  char* p = (char*)d_ws;
  auto alloc = [&](size_t bytes) {
    char* r = p;
    p += (bytes + 255) & ~(size_t)255;
    return r;
  };
  f16*   x16   = (f16*)alloc((size_t)BB * TT * DD * 2);
  f16*   Wcat0 = (f16*)alloc((size_t)NG * K0 * 2);
  f16*   Wcat1 = (f16*)alloc((size_t)NG * K1 * 2);
  float* bcat0 = (float*)alloc((size_t)NG * 4);
  float* bcat1 = (float*)alloc((size_t)NG * 4);
  f16*   h0g   = (f16*)alloc((size_t)2 * BB * HH * 2);
  f16*   h1g   = (f16*)alloc((size_t)2 * BB * HH * 2);
  int*   bar   = (int*)alloc(256);

  if ((size_t)(p - (char*)d_ws) > ws_size) return;  // ws too small: bail cleanly

  hipMemsetAsync(bar, 0, 256, stream);
  hipMemsetAsync(h0g + (size_t)BB * HH, 0, (size_t)BB * HH * 2, stream);  // h0[-1]=0 (parity 1)
  hipMemsetAsync(h1g, 0, (size_t)BB * HH * 2, stream);                    // h1[-1]=0 (parity 0)

  prep_x_kernel<<<dim3(TT * BB * (DD / 4) / 256), dim3(256), 0, stream>>>(x, x16);
  prep_w_kernel<<<dim3(NG * K0 / 4 / 256), dim3(256), 0, stream>>>(Wih0, Whh0, Wcat0, DD, K0);
  prep_w_kernel<<<dim3(NG * K1 / 4 / 256), dim3(256), 0, stream>>>(Wih1, Whh1, Wcat1, HH, K1);
  prep_b_kernel<<<dim3(16), dim3(256), 0, stream>>>(bih0, bhh0, bcat0);
  prep_b_kernel<<<dim3(16), dim3(256), 0, stream>>>(bih1, bhh1, bcat1);

  (void)hipFuncSetAttribute((const void*)lstm_persistent,
                            hipFuncAttributeMaxDynamicSharedMemorySize, DYNLDS);
  lstm_persistent<<<dim3(NB), dim3(256), DYNLDS, stream>>>(
      x16, Wcat0, Wcat1, bcat0, bcat1, h0g, h1g, bar);

  // h0 final: t=255 written at s=255 (parity 1); h1 final: t=255 at s=256 (parity 0)
  fc_kernel<<<dim3(NCLS / 4), dim3(256), 0, stream>>>(
      h0g + (size_t)BB * HH, h1g, Wfc, bfc, out);
}

// Round 4
// 5801.048 us; speedup vs baseline: 1.5864x; 1.3901x over previous
//
#include <hip/hip_runtime.h>

#define BB 64
#define TT 256
#define DD 512
#define HH 1024
#define NG 4096   // 4*H
#define NCLS 1000

#define NB   256   // persistent blocks (== CU count; 1 block/CU via LDS)
#define L0B  128   // blocks 0..127: layer0; 128..255: layer1
#define COLS 8     // h-columns per block
#define K0   (DD + HH)   // 1536
#define K1   (HH + HH)   // 2048
#define LDW0 (K0 + 8)    // +8 halves keeps rows 16B-aligned for b128 reads
#define LDW1 (K1 + 8)
#define DYNLDS (32 * LDW1 * 2)  // 131584 B
#define BARWORDS (NB * 32 + 32) // per-block flag lines + gen line

typedef _Float16 f16;
typedef _Float16 f16x4 __attribute__((ext_vector_type(4)));
typedef _Float16 f16x8 __attribute__((ext_vector_type(8)));
typedef float f32x4 __attribute__((ext_vector_type(4)));

#define MFMA16(af, bf, acc) __builtin_amdgcn_mfma_f32_16x16x32_f16((af), (bf), (acc), 0, 0, 0)
#define FSIG(x) (1.f / (1.f + __expf(-(x))))
#define FTANH(x) (1.f - 2.f / (__expf(2.f * (x)) + 1.f))

// ---- prep: x [B][T][D] fp32 -> x16 [T][B][D] fp16 ----
__global__ __launch_bounds__(256) void prep_x_kernel(const float* __restrict__ x,
                                                     f16* __restrict__ x16) {
  int idx = blockIdx.x * 256 + threadIdx.x;  // over T*B*(D/4)
  int d4  = idx & 127;
  int rem = idx >> 7;
  int b   = rem & 63;
  int t   = rem >> 6;
  float4 v = *(const float4*)(x + ((size_t)b * TT + t) * DD + d4 * 4);
  f16x4 o = {(f16)v.x, (f16)v.y, (f16)v.z, (f16)v.w};
  *(f16x4*)(x16 + ((size_t)t * BB + b) * DD + d4 * 4) = o;
}

// ---- prep: Wcat[j][0:din]=W_ih[j], Wcat[j][din:K]=W_hh[j], fp16 ----
__global__ __launch_bounds__(256) void prep_w_kernel(const float* __restrict__ Wih,
                                                     const float* __restrict__ Whh,
                                                     f16* __restrict__ Wcat,
                                                     int din, int K) {
  int idx = blockIdx.x * 256 + threadIdx.x;
  int kq  = K >> 2;
  int c4  = idx % kq;
  int row = idx / kq;
  if (row >= NG) return;
  int c = c4 * 4;
  const float* src = (c < din) ? (Wih + (size_t)row * din + c)
                               : (Whh + (size_t)row * HH + (c - din));
  float4 v = *(const float4*)src;
  f16x4 o = {(f16)v.x, (f16)v.y, (f16)v.z, (f16)v.w};
  *(f16x4*)(Wcat + (size_t)row * K + c) = o;
}

__global__ __launch_bounds__(256) void prep_b_kernel(const float* __restrict__ bih,
                                                     const float* __restrict__ bhh,
                                                     float* __restrict__ bcat) {
  int idx = blockIdx.x * 256 + threadIdx.x;
  if (idx < NG) bcat[idx] = bih[idx] + bhh[idx];
}

// ---- two-level device-wide barrier ----
// arrive: block's thread0 stamps its own padded flag line (parallel across blocks)
// master (block 0): 256 threads poll the 256 flags in parallel, then publish gen
// others: thread0 polls gen.  Stamps are monotone (s+1) -> no reset race.
__device__ __forceinline__ void gbar(int* flags, int* gen, int s, int bid) {
  __syncthreads();  // all waves' work done; stores drained (vmcnt 0 per wave)
  if (threadIdx.x == 0) {
    __threadfence();  // agent release: wb L2 so h-writes are device-visible
    __hip_atomic_store(flags + bid * 32, s + 1, __ATOMIC_RELAXED,
                       __HIP_MEMORY_SCOPE_AGENT);
  }
  if (bid == 0) {
    int* f = flags + threadIdx.x * 32;
    while (__hip_atomic_load(f, __ATOMIC_RELAXED, __HIP_MEMORY_SCOPE_AGENT) < s + 1) {
    }
    __syncthreads();  // all 256 flags observed
    if (threadIdx.x == 0) {
      __hip_atomic_store(gen, s + 1, __ATOMIC_RELAXED, __HIP_MEMORY_SCOPE_AGENT);
      __threadfence();  // agent acquire: inv L1/L2 before reading new h
    }
  } else if (threadIdx.x == 0) {
    while (__hip_atomic_load(gen, __ATOMIC_RELAXED, __HIP_MEMORY_SCOPE_AGENT) < s + 1)
      __builtin_amdgcn_s_sleep(1);
    __threadfence();  // agent acquire
  }
  __syncthreads();
}

// ---- persistent 2-layer LSTM ----
// Block owns 8 h-cols of one layer; weights (32 rows x K) pinned in LDS.
// Super-step s: layer0 computes t=s, layer1 computes t=s-1. One gbar/step.
// c-state entirely in registers. h double-buffered in global (parity s&1).
__global__ __launch_bounds__(256) void lstm_persistent(
    const f16* __restrict__ x16,
    const f16* __restrict__ Wcat0, const f16* __restrict__ Wcat1,
    const float* __restrict__ bcat0, const float* __restrict__ bcat1,
    f16* __restrict__ h0g, f16* __restrict__ h1g, int* __restrict__ bar) {
  extern __shared__ f16 Wl[];
  const int bid  = blockIdx.x;
  const bool L1  = (bid >= L0B);
  const int j0   = (L1 ? bid - L0B : bid) * COLS;
  const int tid  = threadIdx.x;
  const int wv   = tid >> 6;
  const int lane = tid & 63;
  const int col  = lane & 15;   // C/D: n-index (weight row within tile)
  const int kgrp = lane >> 4;   // C/D: m-subgroup; A/B frag k-chunk
  const int jc   = col & 7;
  const int K    = L1 ? K1 : K0;
  const int LDW  = L1 ? LDW1 : LDW0;
  const f16* Wsrc = L1 ? Wcat1 : Wcat0;
  const float* bc = L1 ? bcat1 : bcat0;

  // prologue: weights -> LDS. row n = gate*8 + jc  (tile0: gates i,f; tile1: g,o)
  for (int n = wv; n < 32; n += 4) {
    const f16* src = Wsrc + (size_t)((n >> 3) * HH + j0 + (n & 7)) * K;
    f16* dst = Wl + (size_t)n * LDW;
    for (int kk = lane * 8; kk < K; kk += 512)
      *(f16x8*)(dst + kk) = *(const f16x8*)(src + kk);
  }
  const float bias0 = bc[((col < 8) ? 0 : 1) * HH + j0 + jc];  // b_i / b_f
  const float bias1 = bc[((col < 8) ? 2 : 3) * HH + j0 + jc];  // b_g / b_o
  __syncthreads();

  const f16* bp0 = Wl + (size_t)col * LDW + kgrp * 8;   // B-frag base, tile0
  const f16* bp1 = bp0 + (size_t)16 * LDW;              // tile1
  const int b16  = wv * 16 + col;        // A-row (batch) this lane loads
  const int bout = wv * 16 + kgrp * 4;   // C-row (batch) base for this lane
  float creg[4] = {0.f, 0.f, 0.f, 0.f};

  int* flags = bar;
  int* gen   = bar + NB * 32;

  for (int s = 0; s <= TT; ++s) {
    const int wrp = s & 1;
    const f16* h0r = h0g + (size_t)(wrp ^ 1) * (BB * HH);
    const f16* h1r = h1g + (size_t)(wrp ^ 1) * (BB * HH);
    f16* hw = (L1 ? h1g : h0g) + (size_t)wrp * (BB * HH);
    const bool active = L1 ? (s >= 1) : (s < TT);
    const int t = L1 ? (s - 1) : s;

    f32x4 acc0 = {0.f, 0.f, 0.f, 0.f};
    f32x4 acc1 = {0.f, 0.f, 0.f, 0.f};

    // pre-barrier: layer0 x-projection part (static input, hides barrier wait)
    if (!L1 && active) {
      const f16* ax = x16 + ((size_t)t * BB + b16) * DD + kgrp * 8;
      #pragma unroll 8
      for (int kg = 0; kg < DD; kg += 32) {
        f16x8 af = *(const f16x8*)(ax + kg);
        acc0 = MFMA16(af, *(const f16x8*)(bp0 + kg), acc0);
        acc1 = MFMA16(af, *(const f16x8*)(bp1 + kg), acc1);
      }
    }

    gbar(flags, gen, s, bid);  // publishes h writes of super-step s-1

    if (active) {
      if (!L1) {
        const f16* ah = h0r + (size_t)b16 * HH + kgrp * 8;
        #pragma unroll 8
        for (int kg = 0; kg < HH; kg += 32) {
          f16x8 af = *(const f16x8*)(ah + kg);
          acc0 = MFMA16(af, *(const f16x8*)(bp0 + DD + kg), acc0);
          acc1 = MFMA16(af, *(const f16x8*)(bp1 + DD + kg), acc1);
        }
      } else {
        const f16* a0 = h0r + (size_t)b16 * HH + kgrp * 8;
        #pragma unroll 8
        for (int kg = 0; kg < HH; kg += 32) {
          f16x8 af = *(const f16x8*)(a0 + kg);
          acc0 = MFMA16(af, *(const f16x8*)(bp0 + kg), acc0);
          acc1 = MFMA16(af, *(const f16x8*)(bp1 + kg), acc1);
        }
        const f16* a1 = h1r + (size_t)b16 * HH + kgrp * 8;
        #pragma unroll 8
        for (int kg = 0; kg < HH; kg += 32) {
          f16x8 af = *(const f16x8*)(a1 + kg);
          acc0 = MFMA16(af, *(const f16x8*)(bp0 + HH + kg), acc0);
          acc1 = MFMA16(af, *(const f16x8*)(bp1 + HH + kg), acc1);
        }
      }
      // elementwise: lane(col<8) holds i (acc0), g (acc1); partner col+8 holds f,o
      #pragma unroll
      for (int r = 0; r < 4; ++r) {
        float p0 = acc0[r] + bias0;
        float p1 = acc1[r] + bias1;
        float q0 = __shfl_xor(p0, 8);
        float q1 = __shfl_xor(p1, 8);
        if (col < 8) {
          float ig = FSIG(p0);
          float gg = FTANH(p1);
          float fg = FSIG(q0);
          float og = FSIG(q1);
          float cc = fg * creg[r] + ig * gg;
          creg[r] = cc;
          hw[(size_t)(bout + r) * HH + j0 + jc] = (f16)(og * FTANH(cc));
        }
      }
    }
  }
}

// ---- FC: logits[b][cls] = b_fc[cls] + sum_k concat(h0,h1)[b][k] * Wfc[cls][k]
__global__ __launch_bounds__(256) void fc_kernel(const f16* __restrict__ h0f,
                                                 const f16* __restrict__ h1f,
                                                 const float* __restrict__ Wfc,
                                                 const float* __restrict__ bfc,
                                                 float* __restrict__ out) {
  __shared__ f16 hl[64][264];
  __shared__ float Wl[4][260];
  const int tid = threadIdx.x;
  const int cl0 = blockIdx.x * 4;
  const int b   = tid >> 2;
  const int cq  = tid & 3;
  float a = 0.f;
  for (int k0 = 0; k0 < 2 * HH; k0 += 256) {
    #pragma unroll
    for (int i = 0; i < 8; i++) {
      int v   = tid + i * 256;
      int row = v >> 5;
      int kk  = (v & 31) * 8;
      int kg  = k0 + kk;
      const f16* src = (kg < HH) ? (h0f + (size_t)row * HH + kg)
                                 : (h1f + (size_t)row * HH + (kg - HH));
      *(f16x8*)(&hl[row][kk]) = *(const f16x8*)src;
    }
    {
      int row = tid >> 6;
      int kk  = (tid & 63) * 4;
      *(float4*)(&Wl[row][kk]) = *(const float4*)(Wfc + (size_t)(cl0 + row) * (2 * HH) + k0 + kk);
    }
    __syncthreads();
    #pragma unroll 8
    for (int k = 0; k < 256; k++) a += (float)hl[b][k] * Wl[cq][k];
    __syncthreads();
  }
  out[(size_t)b * NCLS + cl0 + cq] = a + bfc[cl0 + cq];
}

extern "C" void kernel_launch(void* const* d_in, const int* in_sizes, int n_in,
                              void* d_out, int out_size, void* d_ws, size_t ws_size,
                              hipStream_t stream) {
  const float* x    = (const float*)d_in[0];
  const float* Wih0 = (const float*)d_in[1];
  const float* Whh0 = (const float*)d_in[2];
  const float* bih0 = (const float*)d_in[3];
  const float* bhh0 = (const float*)d_in[4];
  const float* Wih1 = (const float*)d_in[5];
  const float* Whh1 = (const float*)d_in[6];
  const float* bih1 = (const float*)d_in[7];
  const float* bhh1 = (const float*)d_in[8];
  const float* Wfc  = (const float*)d_in[9];
  const float* bfc  = (const float*)d_in[10];
  float* out = (float*)d_out;

  char* p = (char*)d_ws;
  auto alloc = [&](size_t bytes) {
    char* r = p;
    p += (bytes + 255) & ~(size_t)255;
    return r;
  };
  f16*   x16   = (f16*)alloc((size_t)BB * TT * DD * 2);
  f16*   Wcat0 = (f16*)alloc((size_t)NG * K0 * 2);
  f16*   Wcat1 = (f16*)alloc((size_t)NG * K1 * 2);
  float* bcat0 = (float*)alloc((size_t)NG * 4);
  float* bcat1 = (float*)alloc((size_t)NG * 4);
  f16*   h0g   = (f16*)alloc((size_t)2 * BB * HH * 2);
  f16*   h1g   = (f16*)alloc((size_t)2 * BB * HH * 2);
  int*   bar   = (int*)alloc((size_t)BARWORDS * 4);

  if ((size_t)(p - (char*)d_ws) > ws_size) return;  // ws too small: bail cleanly

  hipMemsetAsync(bar, 0, (size_t)BARWORDS * 4, stream);
  hipMemsetAsync(h0g + (size_t)BB * HH, 0, (size_t)BB * HH * 2, stream);  // h0[-1]=0 (parity 1)
  hipMemsetAsync(h1g, 0, (size_t)BB * HH * 2, stream);                    // h1[-1]=0 (parity 0)

  prep_x_kernel<<<dim3(TT * BB * (DD / 4) / 256), dim3(256), 0, stream>>>(x, x16);
  prep_w_kernel<<<dim3(NG * K0 / 4 / 256), dim3(256), 0, stream>>>(Wih0, Whh0, Wcat0, DD, K0);
  prep_w_kernel<<<dim3(NG * K1 / 4 / 256), dim3(256), 0, stream>>>(Wih1, Whh1, Wcat1, HH, K1);
  prep_b_kernel<<<dim3(16), dim3(256), 0, stream>>>(bih0, bhh0, bcat0);
  prep_b_kernel<<<dim3(16), dim3(256), 0, stream>>>(bih1, bhh1, bcat1);

  (void)hipFuncSetAttribute((const void*)lstm_persistent,
                            hipFuncAttributeMaxDynamicSharedMemorySize, DYNLDS);
  lstm_persistent<<<dim3(NB), dim3(256), DYNLDS, stream>>>(
      x16, Wcat0, Wcat1, bcat0, bcat1, h0g, h1g, bar);

  // h0 final: t=255 written at s=255 (parity 1); h1 final: t=255 at s=256 (parity 0)
  fc_kernel<<<dim3(NCLS / 4), dim3(256), 0, stream>>>(
      h0g + (size_t)BB * HH, h1g, Wfc, bfc, out);
}

// Round 5
// 5700.935 us; speedup vs baseline: 1.6142x; 1.0176x over previous
//
#include <hip/hip_runtime.h>

#define BB 64
#define TT 256
#define DD 512
#define HH 1024
#define NCLS 1000

#define NB   256       // persistent blocks (1/CU via LDS)
#define L0B  128       // blocks [0,128): layer0; [128,256): layer1
#define COLS 8         // h-columns per block
#define RING 32        // h ring depth (no-stale-line reuse distance)
#define HSZ  (BB * HH) // elements per h snapshot
#define CHK0 48        // K0/32 chunks (512 x + 1024 h)
#define CHK1 64        // K1/32 chunks (1024 h0 + 1024 h1)
#define TS0  (CHK0 * 512)
#define TS1  (CHK1 * 512)
// LDS: packed W frags (2 tiles) + gate-exchange xbuf + h-bounce hbuf
#define DYNLDS (2 * TS1 * 2 + 4 * 16 * 16 * 4 + 4 * 16 * 8 * 2)  // 136192 B

typedef _Float16 f16;
typedef _Float16 f16x4 __attribute__((ext_vector_type(4)));
typedef _Float16 f16x8 __attribute__((ext_vector_type(8)));
typedef float f32x4 __attribute__((ext_vector_type(4)));

#define MFMA16(af, bf, acc) __builtin_amdgcn_mfma_f32_16x16x32_f16((af), (bf), (acc), 0, 0, 0)
#define FSIG(x) (1.f / (1.f + __expf(-(x))))
#define FTANH(x) (1.f - 2.f / (__expf(2.f * (x)) + 1.f))

// ---- prep: x [B][T][D] fp32 -> x16 [T][B][D] fp16 ----
__global__ __launch_bounds__(256) void prep_x_kernel(const float* __restrict__ x,
                                                     f16* __restrict__ x16) {
  int idx = blockIdx.x * 256 + threadIdx.x;
  int d4  = idx & 127;
  int rem = idx >> 7;
  int b   = rem & 63;
  int t   = rem >> 6;
  float4 v = *(const float4*)(x + ((size_t)b * TT + t) * DD + d4 * 4);
  f16x4 o = {(f16)v.x, (f16)v.y, (f16)v.z, (f16)v.w};
  *(f16x4*)(x16 + ((size_t)t * BB + b) * DD + d4 * 4) = o;
}

// ---- persistent 2-layer LSTM ----
// Block owns 8 h-cols of one layer. Weights packed in LDS in MFMA-fragment
// order (conflict-free ds_read_b128 at lane*16). 8 waves: wt(2 weight tiles:
// {i,f} and {g,o}) x bt(4 batch tiles). h lives in a depth-32 global ring:
// addresses reuse only after 32 steps, so normal cached loads can never see
// a stale line -> no cache-invalidate fences needed. Release flag-store
// (waitcnt+wbl2) publishes h; x16/h stay L2-resident.
__global__ __launch_bounds__(512) void lstm_persistent(
    const f16* __restrict__ x16,
    const float* __restrict__ Wih0, const float* __restrict__ Whh0,
    const float* __restrict__ bih0, const float* __restrict__ bhh0,
    const float* __restrict__ Wih1, const float* __restrict__ Whh1,
    const float* __restrict__ bih1, const float* __restrict__ bhh1,
    f16* __restrict__ h0ring, f16* __restrict__ h1ring, int* __restrict__ bar) {
  extern __shared__ f16 lds[];
  const int bid  = blockIdx.x;
  const bool IS1 = (bid >= L0B);
  const int j0   = (IS1 ? bid - L0B : bid) * COLS;
  const int tid  = threadIdx.x;
  const int wv   = tid >> 6;
  const int lane = tid & 63;
  const int wt   = wv >> 2;     // weight tile: 0={i,f}, 1={g,o}
  const int bt   = wv & 3;      // batch tile (16 rows)
  const int col  = lane & 15;   // A-row within tile / C-D n-index
  const int kgrp = lane >> 4;   // k-chunk subgroup
  const int jc   = col & 7;

  const int   CHK = IS1 ? CHK1 : CHK0;
  const int   TS  = IS1 ? TS1 : TS0;
  const int   DIN = IS1 ? HH : DD;
  f16* Wpk    = lds;
  float* xbuf = (float*)(lds + 2 * TS1);          // [4][16][16] f32
  f16* hbuf   = (f16*)(xbuf + 4 * 16 * 16);       // [4][16][8]

  // ---- prologue: pack weights into fragment order (fp32 -> fp16) ----
  {
    const float* Wi = IS1 ? Wih1 : Wih0;
    const float* Wh = IS1 ? Whh1 : Whh0;
    const int grow = (wt * 2 + ((lane & 15) >> 3)) * HH + j0 + (lane & 7);
    const float* rowi = Wi + (size_t)grow * DIN;
    const float* rowh = Wh + (size_t)grow * HH;
    for (int ck = bt; ck < CHK; ck += 4) {
      int k = ck * 32 + kgrp * 8;
      const float* src = (k < DIN) ? (rowi + k) : (rowh + (k - DIN));
      float4 u = *(const float4*)src;
      float4 v = *(const float4*)(src + 4);
      f16x8 w = {(f16)u.x, (f16)u.y, (f16)u.z, (f16)u.w,
                 (f16)v.x, (f16)v.y, (f16)v.z, (f16)v.w};
      *(f16x8*)(Wpk + (size_t)wt * TS + (size_t)ck * 512 + lane * 8) = w;
    }
  }
  const float* bi = IS1 ? bih1 : bih0;
  const float* bh = IS1 ? bhh1 : bhh0;
  const int bg = wt * 2 + (col >> 3);                  // gate for this lane
  const float bias = bi[bg * HH + j0 + jc] + bh[bg * HH + j0 + jc];
  __syncthreads();

  const int arow = bt * 16 + col;   // this lane's A (batch) row
  float creg[4] = {0.f, 0.f, 0.f, 0.f};
  int* flags = bar;
  int* gen   = bar + NB * 32;

  for (int s = 0; s <= TT; ++s) {
    const bool active = IS1 ? (s >= 1) : (s < TT);

    // ---- barrier arrive (publishes h stores of step s-1 via release) ----
    __syncthreads();
    if (tid == 0)
      __hip_atomic_store(flags + bid * 32, s + 1, __ATOMIC_RELEASE,
                         __HIP_MEMORY_SCOPE_AGENT);

    // ---- overlap: layer0 x-projection (reads only x16) ----
    f32x4 acc = {0.f, 0.f, 0.f, 0.f};
    if (!IS1 && active) {
      const f16* ax = x16 + ((size_t)s * BB + arow) * DD + kgrp * 8;
      const f16* bq = Wpk + (size_t)wt * TS + lane * 8;
      #pragma unroll
      for (int ck = 0; ck < 16; ++ck)
        acc = MFMA16(*(const f16x8*)(ax + ck * 32),
                     *(const f16x8*)(bq + (size_t)ck * 512), acc);
    }

    // ---- barrier complete ----
    if (bid == 0) {
      if (tid < NB)
        while (__hip_atomic_load(flags + tid * 32, __ATOMIC_RELAXED,
                                 __HIP_MEMORY_SCOPE_AGENT) < s + 1) {
        }
      __syncthreads();
      if (tid == 0)
        __hip_atomic_store(gen, s + 1, __ATOMIC_RELEASE,
                           __HIP_MEMORY_SCOPE_AGENT);
    } else {
      if (tid == 0)
        while (__hip_atomic_load(gen, __ATOMIC_RELAXED,
                                 __HIP_MEMORY_SCOPE_AGENT) < s + 1)
          __builtin_amdgcn_s_sleep(1);
      __syncthreads();
    }

    if (active) {
      const f16* h0p = h0ring + (size_t)((s - 1) & (RING - 1)) * HSZ +
                       (size_t)arow * HH + kgrp * 8;
      if (!IS1) {
        const f16* bq = Wpk + (size_t)wt * TS + (size_t)16 * 512 + lane * 8;
        #pragma unroll 16
        for (int ck = 0; ck < 32; ++ck)
          acc = MFMA16(*(const f16x8*)(h0p + ck * 32),
                       *(const f16x8*)(bq + (size_t)ck * 512), acc);
      } else {
        const f16* h1p = h1ring + (size_t)((s - 2) & (RING - 1)) * HSZ +
                         (size_t)arow * HH + kgrp * 8;
        const f16* bq = Wpk + (size_t)wt * TS + lane * 8;
        #pragma unroll 16
        for (int ck = 0; ck < 32; ++ck)
          acc = MFMA16(*(const f16x8*)(h0p + ck * 32),
                       *(const f16x8*)(bq + (size_t)ck * 512), acc);
        #pragma unroll 16
        for (int ck = 0; ck < 32; ++ck)
          acc = MFMA16(*(const f16x8*)(h1p + ck * 32),
                       *(const f16x8*)(bq + (size_t)(32 + ck) * 512), acc);
      }

      // ---- gate exchange: wave wt=1 publishes tanh(g) / sig(o) ----
      if (wt == 1) {
        #pragma unroll
        for (int r = 0; r < 4; ++r) {
          float p = acc[r] + bias;
          float a = (col < 8) ? FTANH(p) : FSIG(p);
          xbuf[((size_t)bt * 16 + kgrp * 4 + r) * 16 + col] = a;
        }
      }
      __syncthreads();
      // ---- cell update in wave wt=0 (holds i,f and the c-state) ----
      if (wt == 0) {
        #pragma unroll
        for (int r = 0; r < 4; ++r) {
          float p = acc[r] + bias;
          float q = __shfl_xor(p, 8);     // partner col+8 holds f-pre
          if (col < 8) {
            float ig = FSIG(p);
            float fg = FSIG(q);
            const float* xb = xbuf + ((size_t)bt * 16 + kgrp * 4 + r) * 16;
            float gg = xb[jc];
            float og = xb[8 + jc];
            float cc = fg * creg[r] + ig * gg;
            creg[r] = cc;
            hbuf[((size_t)bt * 16 + kgrp * 4 + r) * 8 + jc] = (f16)(og * FTANH(cc));
          }
        }
        // wave-internal transpose bounce -> contiguous 16B h store
        f16* hw = (IS1 ? h1ring + (size_t)((s - 1) & (RING - 1)) * HSZ
                       : h0ring + (size_t)(s & (RING - 1)) * HSZ);
        if (lane < 16) {
          f16x8 hv = *(const f16x8*)(hbuf + ((size_t)bt * 16 + lane) * 8);
          *(f16x8*)(hw + (size_t)(bt * 16 + lane) * HH + j0) = hv;
        }
      }
    }
  }
}

// ---- FC: logits[b][cls] = b_fc[cls] + sum_k concat(h0,h1)[b][k] * Wfc[cls][k]
__global__ __launch_bounds__(256) void fc_kernel(const f16* __restrict__ h0f,
                                                 const f16* __restrict__ h1f,
                                                 const float* __restrict__ Wfc,
                                                 const float* __restrict__ bfc,
                                                 float* __restrict__ out) {
  __shared__ f16 hl[64][264];
  __shared__ float Wl[4][260];
  const int tid = threadIdx.x;
  const int cl0 = blockIdx.x * 4;
  const int b   = tid >> 2;
  const int cq  = tid & 3;
  float a = 0.f;
  for (int k0 = 0; k0 < 2 * HH; k0 += 256) {
    #pragma unroll
    for (int i = 0; i < 8; i++) {
      int v   = tid + i * 256;
      int row = v >> 5;
      int kk  = (v & 31) * 8;
      int kg  = k0 + kk;
      const f16* src = (kg < HH) ? (h0f + (size_t)row * HH + kg)
                                 : (h1f + (size_t)row * HH + (kg - HH));
      *(f16x8*)(&hl[row][kk]) = *(const f16x8*)src;
    }
    {
      int row = tid >> 6;
      int kk  = (tid & 63) * 4;
      *(float4*)(&Wl[row][kk]) = *(const float4*)(Wfc + (size_t)(cl0 + row) * (2 * HH) + k0 + kk);
    }
    __syncthreads();
    #pragma unroll 8
    for (int k = 0; k < 256; k++) a += (float)hl[b][k] * Wl[cq][k];
    __syncthreads();
  }
  out[(size_t)b * NCLS + cl0 + cq] = a + bfc[cl0 + cq];
}

extern "C" void kernel_launch(void* const* d_in, const int* in_sizes, int n_in,
                              void* d_out, int out_size, void* d_ws, size_t ws_size,
                              hipStream_t stream) {
  const float* x    = (const float*)d_in[0];
  const float* Wih0 = (const float*)d_in[1];
  const float* Whh0 = (const float*)d_in[2];
  const float* bih0 = (const float*)d_in[3];
  const float* bhh0 = (const float*)d_in[4];
  const float* Wih1 = (const float*)d_in[5];
  const float* Whh1 = (const float*)d_in[6];
  const float* bih1 = (const float*)d_in[7];
  const float* bhh1 = (const float*)d_in[8];
  const float* Wfc  = (const float*)d_in[9];
  const float* bfc  = (const float*)d_in[10];
  float* out = (float*)d_out;

  char* p = (char*)d_ws;
  auto alloc = [&](size_t bytes) {
    char* r = p;
    p += (bytes + 255) & ~(size_t)255;
    return r;
  };
  f16* x16    = (f16*)alloc((size_t)BB * TT * DD * 2);
  f16* h0ring = (f16*)alloc((size_t)RING * HSZ * 2);
  f16* h1ring = (f16*)alloc((size_t)RING * HSZ * 2);
  int* bar    = (int*)alloc((size_t)(NB * 32 + 32) * 4);

  if ((size_t)(p - (char*)d_ws) > ws_size) return;  // ws too small: bail cleanly

  hipMemsetAsync(bar, 0, (size_t)(NB * 32 + 32) * 4, stream);
  // slot 31 = t=-1 zeros for both rings (overwritten at t=31 after consumers done)
  hipMemsetAsync(h0ring + (size_t)(RING - 1) * HSZ, 0, (size_t)HSZ * 2, stream);
  hipMemsetAsync(h1ring + (size_t)(RING - 1) * HSZ, 0, (size_t)HSZ * 2, stream);

  prep_x_kernel<<<dim3(TT * BB * (DD / 4) / 256), dim3(256), 0, stream>>>(x, x16);

  (void)hipFuncSetAttribute((const void*)lstm_persistent,
                            hipFuncAttributeMaxDynamicSharedMemorySize, DYNLDS);
  lstm_persistent<<<dim3(NB), dim3(512), DYNLDS, stream>>>(
      x16, Wih0, Whh0, bih0, bhh0, Wih1, Whh1, bih1, bhh1, h0ring, h1ring, bar);

  // h0[255] -> slot 255&31 = 31; h1[255] (written at s=256) -> slot 31
  fc_kernel<<<dim3(NCLS / 4), dim3(256), 0, stream>>>(
      h0ring + (size_t)(RING - 1) * HSZ, h1ring + (size_t)(RING - 1) * HSZ,
      Wfc, bfc, out);
}